// Round 4
// baseline (2619.429 us; speedup 1.0000x reference)
//
#include <hip/hip_runtime.h>
#include <hip/hip_bf16.h>

// Problem constants
#define TT 16
#define MM 1024
#define HDIM 128
#define NHEADS 4
#define NROWS (TT*MM)          // 16384
#define MAXDEG 64
#define QS 132                 // padded LDS row stride (floats) for q/k/v/hid

// ---------------- mask + neighbor-list build ----------------
__global__ __launch_bounds__(256) void k_init(const int* __restrict__ ego,
                                              float* __restrict__ mfl,
                                              int* __restrict__ cnt) {
    int idx = blockIdx.x * 256 + threadIdx.x;   // < 16384
    int t = idx >> 10, i = idx & 1023;
    int b = i >> 8, n = i & 255;
    mfl[idx] = ego[b * (TT * 256) + t * 256 + n] ? 1.f : 0.f;
    cnt[idx] = 0;
}

__global__ __launch_bounds__(256) void k_edges(const float* __restrict__ adj,
                                               const float* __restrict__ mfl,
                                               int* __restrict__ cnt,
                                               int* __restrict__ nbr) {
    int bid = blockIdx.x;            // 256 blocks: t(16) x jc(4) x ic(4)
    int t = bid >> 4, jc = (bid >> 2) & 3, ic = bid & 3;
    int tid = threadIdx.x;
    int i = ic * 256 + tid;
    int row = t * MM + i;
    __shared__ float ms[256];
    int j0 = jc * 256;
    ms[tid] = mfl[t * MM + j0 + tid];
    __syncthreads();
    float mi = mfl[row];
    if (mi == 0.f) return;
    const float* at = adj + (size_t)t * MM * MM;
    for (int jj = 0; jj < 256; ++jj) {
        int j = j0 + jj;
        bool e;
        if (j == i) e = true;                                   // self-loop
        else e = (at[(size_t)j * MM + i] != 0.f) && (ms[jj] != 0.f);
        if (e) {
            int pos = atomicAdd(&cnt[row], 1);
            if (pos < MAXDEG) nbr[(size_t)row * MAXDEG + pos] = j;
        }
    }
}

// ---------------- GAT layer 1: projection (F=2) + fused ss/sd ----------------
__global__ __launch_bounds__(128) void k_gat1(const float* __restrict__ x,
                                              const float* __restrict__ W,
                                              const float* __restrict__ asrc,
                                              const float* __restrict__ adst,
                                              float* __restrict__ h,
                                              float* __restrict__ ss,
                                              float* __restrict__ sd) {
    int row = blockIdx.x, tid = threadIdx.x;
    float x0 = x[row * 2], x1 = x[row * 2 + 1];
    float s4[4], d4[4];
#pragma unroll
    for (int hh = 0; hh < 4; ++hh) {
        int o = hh * 128 + tid;
        float v = x0 * W[o] + x1 * W[512 + o];
        h[(size_t)row * 512 + o] = v;
        s4[hh] = v * asrc[o];
        d4[hh] = v * adst[o];
    }
#pragma unroll
    for (int hh = 0; hh < 4; ++hh)
        for (int off = 32; off; off >>= 1) {
            s4[hh] += __shfl_down(s4[hh], off, 64);
            d4[hh] += __shfl_down(d4[hh], off, 64);
        }
    __shared__ float red[2][2][4];
    if ((tid & 63) == 0) {
        int w = tid >> 6;
#pragma unroll
        for (int hh = 0; hh < 4; ++hh) { red[w][0][hh] = s4[hh]; red[w][1][hh] = d4[hh]; }
    }
    __syncthreads();
    if (tid < 4) ss[row * 4 + tid] = red[0][0][tid] + red[1][0][tid];
    else if (tid < 8) sd[row * 4 + tid - 4] = red[0][1][tid - 4] + red[1][1][tid - 4];
}

// ---------------- GAT layers 2-6: 32 rows/block, float4 weight loads ----------------
__global__ __launch_bounds__(512, 4) void k_gat_h(const float* __restrict__ x,
                                                  const float* __restrict__ W,
                                                  const float* __restrict__ asrc,
                                                  const float* __restrict__ adst,
                                                  float* __restrict__ h,
                                                  float* __restrict__ ss,
                                                  float* __restrict__ sd) {
    __shared__ __align__(16) float Xs[4096];
    int row0 = blockIdx.x * 32, tid = threadIdx.x;
    int og = tid & 31, rg = tid >> 5, r0 = rg * 2;
    for (int idx = tid; idx < 4096; idx += 512)
        Xs[idx] = x[(size_t)row0 * 128 + idx];
    __syncthreads();
    for (int c = 0; c < 4; ++c) {       // head chunk = 128 output cols
        float acc[2][4];
#pragma unroll
        for (int r = 0; r < 2; ++r)
#pragma unroll
            for (int j = 0; j < 4; ++j) acc[r][j] = 0.f;
        for (int k = 0; k < 128; k += 4) {
            float4 xv0 = *(const float4*)(Xs + r0 * 128 + k);
            float4 xv1 = *(const float4*)(Xs + (r0 + 1) * 128 + k);
#pragma unroll
            for (int kk = 0; kk < 4; ++kk) {
                float4 w = *(const float4*)(W + (k + kk) * 512 + c * 128 + 4 * og);
                float a0 = (&xv0.x)[kk], a1 = (&xv1.x)[kk];
                acc[0][0] += a0 * w.x; acc[0][1] += a0 * w.y; acc[0][2] += a0 * w.z; acc[0][3] += a0 * w.w;
                acc[1][0] += a1 * w.x; acc[1][1] += a1 * w.y; acc[1][2] += a1 * w.z; acc[1][3] += a1 * w.w;
            }
        }
        const float* ap = asrc + c * 128 + 4 * og;
        const float* dp = adst + c * 128 + 4 * og;
#pragma unroll
        for (int r = 0; r < 2; ++r) {
            *(float4*)(h + (size_t)(row0 + r0 + r) * 512 + c * 128 + 4 * og) =
                make_float4(acc[r][0], acc[r][1], acc[r][2], acc[r][3]);
            float s = acc[r][0] * ap[0] + acc[r][1] * ap[1] + acc[r][2] * ap[2] + acc[r][3] * ap[3];
            float d = acc[r][0] * dp[0] + acc[r][1] * dp[1] + acc[r][2] * dp[2] + acc[r][3] * dp[3];
#pragma unroll
            for (int off = 16; off; off >>= 1) {
                s += __shfl_xor(s, off, 32);
                d += __shfl_xor(d, off, 32);
            }
            if (og == 0) {
                ss[(row0 + r0 + r) * 4 + c] = s;
                sd[(row0 + r0 + r) * 4 + c] = d;
            }
        }
    }
}

// ---------------- GAT aggregation (segment softmax + gather) ----------------
__global__ __launch_bounds__(128) void k_agg(const float* __restrict__ h,
                                             const float* __restrict__ ss,
                                             const float* __restrict__ sd,
                                             const int* __restrict__ cnt,
                                             const int* __restrict__ nbr,
                                             const float* __restrict__ mfl,
                                             const float* __restrict__ bias,
                                             float* __restrict__ xo) {
    int row = blockIdx.x, tid = threadIdx.x;
    int t = row >> 10;
    if (mfl[row] == 0.f) { xo[(size_t)row * 128 + tid] = 0.f; return; }
    int c = cnt[row]; if (c > MAXDEG) c = MAXDEG;
    __shared__ int nb[MAXDEG];
    __shared__ float al[MAXDEG][4];
    if (tid < c) nb[tid] = nbr[(size_t)row * MAXDEG + tid];
    __syncthreads();
    for (int idx = tid; idx < c * 4; idx += 128) {
        int n = idx >> 2, hh = idx & 3, j = nb[n];
        float lg = sd[row * 4 + hh] + ss[(t * MM + j) * 4 + hh];
        al[n][hh] = lg > 0.f ? lg : 0.2f * lg;   // leaky_relu 0.2
    }
    __syncthreads();
    if (tid < 4) {
        float mx = -1e30f;
        for (int n = 0; n < c; ++n) mx = fmaxf(mx, al[n][tid]);
        float s = 0.f;
        for (int n = 0; n < c; ++n) { float e = __expf(al[n][tid] - mx); al[n][tid] = e; s += e; }
        float inv = 1.f / s;
        for (int n = 0; n < c; ++n) al[n][tid] *= inv;
    }
    __syncthreads();
    float a0 = 0, a1 = 0, a2 = 0, a3 = 0;
    for (int n = 0; n < c; ++n) {
        int j = nb[n];
        const float* hp = h + ((size_t)(t * MM + j)) * 512 + tid;
        a0 += al[n][0] * hp[0];
        a1 += al[n][1] * hp[128];
        a2 += al[n][2] * hp[256];
        a3 += al[n][3] * hp[384];
    }
    float v = 0.25f * (a0 + a1 + a2 + a3) + bias[tid];
    xo[(size_t)row * 128 + tid] = fmaxf(v, 0.f);
}

// ---------------- in-place LayerNorm, 32 rows x 128, 512 threads ----------------
__device__ __forceinline__ void ln512(float* xs, const float* s, const float* b) {
    int tid = threadIdx.x, row = tid >> 4, lane = tid & 15;
    float* xr = xs + row * 128;
    float sum = 0.f;
#pragma unroll
    for (int k2 = 0; k2 < 8; ++k2) sum += xr[lane + 16 * k2];
#pragma unroll
    for (int off = 8; off; off >>= 1) sum += __shfl_xor(sum, off, 16);
    float mean = sum * (1.f / 128.f);
    float vs = 0.f;
#pragma unroll
    for (int k2 = 0; k2 < 8; ++k2) { float d = xr[lane + 16 * k2] - mean; vs += d * d; }
#pragma unroll
    for (int off = 8; off; off >>= 1) vs += __shfl_xor(vs, off, 16);
    float rstd = rsqrtf(vs * (1.f / 128.f) + 1e-5f);
#pragma unroll
    for (int k2 = 0; k2 < 8; ++k2) {
        int d = lane + 16 * k2;
        float v = (xr[d] - mean) * rstd;
        xr[d] = v * s[d] + b[d];
    }
    __syncthreads();
}

// ---------------- 5-layer transformer, 2 sequences per 512-thread block ----------------
// LDS = 4096 + 3*32*132 + 2048 = 18816 floats = 75264 B -> 2 blocks/CU, 16 waves/CU.
__global__ __launch_bounds__(512, 4) void k_tf(const float* __restrict__ xg,
        const float* __restrict__ Wqkv, const float* __restrict__ bqkv,
        const float* __restrict__ Wo,   const float* __restrict__ bo,
        const float* __restrict__ ln1s, const float* __restrict__ ln1b,
        const float* __restrict__ ln2s, const float* __restrict__ ln2b,
        const float* __restrict__ Wff1, const float* __restrict__ bff1,
        const float* __restrict__ Wff2, const float* __restrict__ bff2,
        float* __restrict__ out) {
    __shared__ __align__(16) float xs[4096];        // residual, 32 rows x 128
    __shared__ __align__(16) float qb[32 * QS];     // Q / attn-out
    __shared__ __align__(16) float kb[32 * QS];     // K / FF1 hidden chunk
    __shared__ __align__(16) float vb[32 * QS];     // V / FF2 accumulator
    __shared__ __align__(16) float scr[2048];       // P transposed: [tk][seq*64+h*16+tq]
    int m = blockIdx.x, tid = threadIdx.x;
    const int og = tid & 31, rg = tid >> 5, r0 = rg * 2;

    // load + sinusoidal PE
    for (int idx = tid; idx < 4096; idx += 512) {
        int seq = idx >> 11, t = (idx >> 7) & 15, d = idx & 127, jj = d >> 1;
        float arg = (float)t * expf(-(float)(2 * jj) * (9.210340371976184f / 128.f));
        float pe = (d & 1) ? cosf(arg) : sinf(arg);
        xs[idx] = xg[(size_t)t * (MM * HDIM) + (size_t)(2 * m + seq) * HDIM + d] + pe;
    }
    __syncthreads();

    for (int l = 0; l < 5; ++l) {
        // ---- fused QKV: [32,128]@[128,3*128] ----
        {
            float acc[2][3][4];
#pragma unroll
            for (int r = 0; r < 2; ++r)
#pragma unroll
                for (int mt = 0; mt < 3; ++mt)
#pragma unroll
                    for (int j = 0; j < 4; ++j) acc[r][mt][j] = 0.f;
            const float* Wl = Wqkv + (size_t)l * 49152;
            for (int k = 0; k < 128; k += 4) {
                float4 xv0 = *(const float4*)(xs + r0 * 128 + k);
                float4 xv1 = *(const float4*)(xs + (r0 + 1) * 128 + k);
#pragma unroll
                for (int kk = 0; kk < 4; ++kk) {
                    float a0 = (&xv0.x)[kk], a1 = (&xv1.x)[kk];
#pragma unroll
                    for (int mt = 0; mt < 3; ++mt) {
                        float4 w = *(const float4*)(Wl + mt * 16384 + (k + kk) * 128 + 4 * og);
                        acc[0][mt][0] += a0 * w.x; acc[0][mt][1] += a0 * w.y;
                        acc[0][mt][2] += a0 * w.z; acc[0][mt][3] += a0 * w.w;
                        acc[1][mt][0] += a1 * w.x; acc[1][mt][1] += a1 * w.y;
                        acc[1][mt][2] += a1 * w.z; acc[1][mt][3] += a1 * w.w;
                    }
                }
            }
#pragma unroll
            for (int mt = 0; mt < 3; ++mt) {
                float* ob = (mt == 0) ? qb : (mt == 1) ? kb : vb;
                const float* bp = bqkv + l * 384 + mt * 128 + 4 * og;
                float4 bb = *(const float4*)bp;
#pragma unroll
                for (int r = 0; r < 2; ++r)
                    *(float4*)(ob + (r0 + r) * QS + 4 * og) =
                        make_float4(acc[r][mt][0] + bb.x, acc[r][mt][1] + bb.y,
                                    acc[r][mt][2] + bb.z, acc[r][mt][3] + bb.w);
            }
        }
        __syncthreads();
        // ---- scores: thread = (seq,h,tq,tk0..tk0+3) ----
        {
            int seq = tid >> 8, hh = (tid >> 6) & 3, tq = (tid >> 2) & 15, tk0 = (tid & 3) * 4;
            const float* qp = qb + (seq * 16 + tq) * QS + hh * 32;
            float a[4] = {0.f, 0.f, 0.f, 0.f};
#pragma unroll
            for (int d = 0; d < 8; ++d) {
                float4 q4 = *(const float4*)(qp + 4 * d);
#pragma unroll
                for (int j = 0; j < 4; ++j) {
                    float4 k4 = *(const float4*)(kb + (seq * 16 + tk0 + j) * QS + hh * 32 + 4 * d);
                    a[j] += q4.x * k4.x + q4.y * k4.y + q4.z * k4.z + q4.w * k4.w;
                }
            }
            int rowid = tid >> 2;   // = seq*64 + hh*16 + tq
#pragma unroll
            for (int j = 0; j < 4; ++j)
                scr[(tk0 + j) * 128 + rowid] = a[j] * 0.17677669529663687f;  // 1/sqrt(32)
        }
        __syncthreads();
        if (tid < 128) {   // softmax per (seq,h,tq) row, coalesced down columns
            float mx = -1e30f;
#pragma unroll
            for (int u = 0; u < 16; ++u) mx = fmaxf(mx, scr[u * 128 + tid]);
            float s = 0.f;
#pragma unroll
            for (int u = 0; u < 16; ++u) { float e = __expf(scr[u * 128 + tid] - mx); scr[u * 128 + tid] = e; s += e; }
            float inv = 1.f / s;
#pragma unroll
            for (int u = 0; u < 16; ++u) scr[u * 128 + tid] *= inv;
        }
        __syncthreads();
        // ---- O = P @ V -> qb ----
        {
            int seq = r0 >> 4, t = r0 & 15, hh = og >> 3;
            const float* pp = scr + seq * 64 + hh * 16;
            float a0[4] = {0.f, 0.f, 0.f, 0.f}, a1[4] = {0.f, 0.f, 0.f, 0.f};
            for (int u = 0; u < 16; ++u) {
                float4 v4 = *(const float4*)(vb + (seq * 16 + u) * QS + 4 * og);
                float p0 = pp[u * 128 + t], p1 = pp[u * 128 + t + 1];
                a0[0] += p0 * v4.x; a0[1] += p0 * v4.y; a0[2] += p0 * v4.z; a0[3] += p0 * v4.w;
                a1[0] += p1 * v4.x; a1[1] += p1 * v4.y; a1[2] += p1 * v4.z; a1[3] += p1 * v4.w;
            }
            *(float4*)(qb + r0 * QS + 4 * og) = make_float4(a0[0], a0[1], a0[2], a0[3]);
            *(float4*)(qb + (r0 + 1) * QS + 4 * og) = make_float4(a1[0], a1[1], a1[2], a1[3]);
        }
        __syncthreads();
        // ---- Wo: accumulate into residual xs ----
        {
            float acc[2][4];
#pragma unroll
            for (int r = 0; r < 2; ++r)
#pragma unroll
                for (int j = 0; j < 4; ++j) acc[r][j] = 0.f;
            const float* Wl = Wo + (size_t)l * 16384;
            for (int k = 0; k < 128; k += 4) {
                float4 xv0 = *(const float4*)(qb + r0 * QS + k);
                float4 xv1 = *(const float4*)(qb + (r0 + 1) * QS + k);
#pragma unroll
                for (int kk = 0; kk < 4; ++kk) {
                    float4 w = *(const float4*)(Wl + (k + kk) * 128 + 4 * og);
                    float a0 = (&xv0.x)[kk], a1 = (&xv1.x)[kk];
                    acc[0][0] += a0 * w.x; acc[0][1] += a0 * w.y; acc[0][2] += a0 * w.z; acc[0][3] += a0 * w.w;
                    acc[1][0] += a1 * w.x; acc[1][1] += a1 * w.y; acc[1][2] += a1 * w.z; acc[1][3] += a1 * w.w;
                }
            }
            float4 bb = *(const float4*)(bo + l * 128 + 4 * og);
#pragma unroll
            for (int r = 0; r < 2; ++r) {
                float* xp = xs + (r0 + r) * 128 + 4 * og;
                xp[0] += acc[r][0] + bb.x; xp[1] += acc[r][1] + bb.y;
                xp[2] += acc[r][2] + bb.z; xp[3] += acc[r][3] + bb.w;
            }
        }
        __syncthreads();
        ln512(xs, ln1s + l * 128, ln1b + l * 128);
        // ---- FF: 4 chunks of 128 hidden cols; hid->kb, accum->vb ----
        for (int c = 0; c < 4; ++c) {
            {
                float acc[2][4];
#pragma unroll
                for (int r = 0; r < 2; ++r)
#pragma unroll
                    for (int j = 0; j < 4; ++j) acc[r][j] = 0.f;
                const float* W1 = Wff1 + (size_t)l * 65536 + c * 128;
                for (int k = 0; k < 128; k += 4) {
                    float4 xv0 = *(const float4*)(xs + r0 * 128 + k);
                    float4 xv1 = *(const float4*)(xs + (r0 + 1) * 128 + k);
#pragma unroll
                    for (int kk = 0; kk < 4; ++kk) {
                        float4 w = *(const float4*)(W1 + (k + kk) * 512 + 4 * og);
                        float a0 = (&xv0.x)[kk], a1 = (&xv1.x)[kk];
                        acc[0][0] += a0 * w.x; acc[0][1] += a0 * w.y; acc[0][2] += a0 * w.z; acc[0][3] += a0 * w.w;
                        acc[1][0] += a1 * w.x; acc[1][1] += a1 * w.y; acc[1][2] += a1 * w.z; acc[1][3] += a1 * w.w;
                    }
                }
                float4 bb = *(const float4*)(bff1 + l * 512 + c * 128 + 4 * og);
#pragma unroll
                for (int r = 0; r < 2; ++r)
                    *(float4*)(kb + (r0 + r) * QS + 4 * og) =
                        make_float4(fmaxf(acc[r][0] + bb.x, 0.f), fmaxf(acc[r][1] + bb.y, 0.f),
                                    fmaxf(acc[r][2] + bb.z, 0.f), fmaxf(acc[r][3] + bb.w, 0.f));
            }
            __syncthreads();
            {
                float acc[2][4];
#pragma unroll
                for (int r = 0; r < 2; ++r)
#pragma unroll
                    for (int j = 0; j < 4; ++j) acc[r][j] = 0.f;
                const float* W2 = Wff2 + (size_t)l * 65536 + (size_t)c * 16384;
                for (int k = 0; k < 128; k += 4) {
                    float4 xv0 = *(const float4*)(kb + r0 * QS + k);
                    float4 xv1 = *(const float4*)(kb + (r0 + 1) * QS + k);
#pragma unroll
                    for (int kk = 0; kk < 4; ++kk) {
                        float4 w = *(const float4*)(W2 + (k + kk) * 128 + 4 * og);
                        float a0 = (&xv0.x)[kk], a1 = (&xv1.x)[kk];
                        acc[0][0] += a0 * w.x; acc[0][1] += a0 * w.y; acc[0][2] += a0 * w.z; acc[0][3] += a0 * w.w;
                        acc[1][0] += a1 * w.x; acc[1][1] += a1 * w.y; acc[1][2] += a1 * w.z; acc[1][3] += a1 * w.w;
                    }
                }
                if (c == 0) {
                    float4 bb = *(const float4*)(bff2 + l * 128 + 4 * og);
#pragma unroll
                    for (int r = 0; r < 2; ++r)
                        *(float4*)(vb + (r0 + r) * QS + 4 * og) =
                            make_float4(acc[r][0] + bb.x, acc[r][1] + bb.y,
                                        acc[r][2] + bb.z, acc[r][3] + bb.w);
                } else {
#pragma unroll
                    for (int r = 0; r < 2; ++r) {
                        float* vp = vb + (r0 + r) * QS + 4 * og;
                        vp[0] += acc[r][0]; vp[1] += acc[r][1]; vp[2] += acc[r][2]; vp[3] += acc[r][3];
                    }
                }
            }
            __syncthreads();
        }
        for (int idx = tid; idx < 4096; idx += 512)
            xs[idx] += vb[(idx >> 7) * QS + (idx & 127)];
        __syncthreads();
        ln512(xs, ln2s + l * 128, ln2b + l * 128);
    }
    for (int idx = tid; idx < 4096; idx += 512)
        out[(size_t)(2 * m + (idx >> 11)) * 2048 + (idx & 2047)] = xs[idx];
}

extern "C" void kernel_launch(void* const* d_in, const int* in_sizes, int n_in,
                              void* d_out, int out_size, void* d_ws, size_t ws_size,
                              hipStream_t stream) {
    (void)in_sizes; (void)n_in; (void)out_size; (void)ws_size;
    const int*   ego  = (const int*)d_in[0];
    const float* pos  = (const float*)d_in[1];
    const float* adj  = (const float*)d_in[2];
    const float* g1W  = (const float*)d_in[3];
    const float* g1as = (const float*)d_in[4];
    const float* g1ad = (const float*)d_in[5];
    const float* g1b  = (const float*)d_in[6];
    const float* gW   = (const float*)d_in[7];
    const float* gas  = (const float*)d_in[8];
    const float* gad  = (const float*)d_in[9];
    const float* gb   = (const float*)d_in[10];
    const float* Wqkv = (const float*)d_in[11];
    const float* bqkv = (const float*)d_in[12];
    const float* Wo   = (const float*)d_in[13];
    const float* bo   = (const float*)d_in[14];
    const float* l1s  = (const float*)d_in[15];
    const float* l1b  = (const float*)d_in[16];
    const float* l2s  = (const float*)d_in[17];
    const float* l2b  = (const float*)d_in[18];
    const float* Wff1 = (const float*)d_in[19];
    const float* bff1 = (const float*)d_in[20];
    const float* Wff2 = (const float*)d_in[21];
    const float* bff2 = (const float*)d_in[22];

    float* ws  = (float*)d_ws;
    float* x0  = ws;                       // 2,097,152 f
    float* x1  = x0 + 2097152;             // 2,097,152 f
    float* hb  = x1 + 2097152;             // 8,388,608 f
    float* ssb = hb + 8388608;             // 65,536 f
    float* sdb = ssb + 65536;              // 65,536 f
    float* mfl = sdb + 65536;              // 16,384 f
    int*   cnt = (int*)(mfl + 16384);      // 16,384 i
    int*   nbr = cnt + 16384;              // 1,048,576 i   (total ~55.2 MB)

    k_init<<<64, 256, 0, stream>>>(ego, mfl, cnt);
    k_edges<<<256, 256, 0, stream>>>(adj, mfl, cnt, nbr);

    // GAT layer 1 (F=2), projection + ss/sd fused
    k_gat1<<<NROWS, 128, 0, stream>>>(pos, g1W, g1as, g1ad, hb, ssb, sdb);
    k_agg<<<NROWS, 128, 0, stream>>>(hb, ssb, sdb, cnt, nbr, mfl, g1b, x0);

    float* xin = x0; float* xout = x1;
    for (int L = 0; L < 5; ++L) {
        k_gat_h<<<512, 512, 0, stream>>>(xin, gW + (size_t)L * 65536,
                                         gas + L * 512, gad + L * 512, hb, ssb, sdb);
        k_agg<<<NROWS, 128, 0, stream>>>(hb, ssb, sdb, cnt, nbr, mfl, gb + L * 128, xout);
        float* tmp = xin; xin = xout; xout = tmp;
    }

    k_tf<<<512, 512, 0, stream>>>(xin, Wqkv, bqkv, Wo, bo, l1s, l1b, l2s, l2b,
                                  Wff1, bff1, Wff2, bff2, (float*)d_out);
}

// Round 5
// 1793.479 us; speedup vs baseline: 1.4605x; 1.4605x over previous
//
#include <hip/hip_runtime.h>
#include <hip/hip_bf16.h>

// Problem constants
#define TT 16
#define MM 1024
#define HDIM 128
#define NHEADS 4
#define NROWS (TT*MM)          // 16384
#define MAXDEG 64

// ---------------- mask + neighbor-list build ----------------
__global__ __launch_bounds__(256) void k_init(const int* __restrict__ ego,
                                              float* __restrict__ mfl,
                                              int* __restrict__ cnt) {
    int idx = blockIdx.x * 256 + threadIdx.x;   // < 16384
    int t = idx >> 10, i = idx & 1023;
    int b = i >> 8, n = i & 255;
    mfl[idx] = ego[b * (TT * 256) + t * 256 + n] ? 1.f : 0.f;
    cnt[idx] = 0;
}

__global__ __launch_bounds__(256) void k_edges(const float* __restrict__ adj,
                                               const float* __restrict__ mfl,
                                               int* __restrict__ cnt,
                                               int* __restrict__ nbr) {
    int bid = blockIdx.x;            // 256 blocks: t(16) x jc(4) x ic(4)
    int t = bid >> 4, jc = (bid >> 2) & 3, ic = bid & 3;
    int tid = threadIdx.x;
    int i = ic * 256 + tid;
    int row = t * MM + i;
    __shared__ float ms[256];
    int j0 = jc * 256;
    ms[tid] = mfl[t * MM + j0 + tid];
    __syncthreads();
    float mi = mfl[row];
    if (mi == 0.f) return;
    const float* at = adj + (size_t)t * MM * MM;
    for (int jj = 0; jj < 256; ++jj) {
        int j = j0 + jj;
        bool e;
        if (j == i) e = true;                                   // self-loop
        else e = (at[(size_t)j * MM + i] != 0.f) && (ms[jj] != 0.f);
        if (e) {
            int pos = atomicAdd(&cnt[row], 1);
            if (pos < MAXDEG) nbr[(size_t)row * MAXDEG + pos] = j;
        }
    }
}

// ---------------- GAT layer 1: projection (F=2) + fused ss/sd ----------------
__global__ __launch_bounds__(128) void k_gat1(const float* __restrict__ x,
                                              const float* __restrict__ W,
                                              const float* __restrict__ asrc,
                                              const float* __restrict__ adst,
                                              float* __restrict__ h,
                                              float* __restrict__ ss,
                                              float* __restrict__ sd) {
    int bid = blockIdx.x;
    int row = ((bid & 7) << 11) + (bid >> 3);   // XCD-locality swizzle
    int tid = threadIdx.x;
    float x0 = x[row * 2], x1 = x[row * 2 + 1];
    float s4[4], d4[4];
#pragma unroll
    for (int hh = 0; hh < 4; ++hh) {
        int o = hh * 128 + tid;
        float v = x0 * W[o] + x1 * W[512 + o];
        h[(size_t)row * 512 + o] = v;
        s4[hh] = v * asrc[o];
        d4[hh] = v * adst[o];
    }
#pragma unroll
    for (int hh = 0; hh < 4; ++hh)
        for (int off = 32; off; off >>= 1) {
            s4[hh] += __shfl_down(s4[hh], off, 64);
            d4[hh] += __shfl_down(d4[hh], off, 64);
        }
    __shared__ float red[2][2][4];
    if ((tid & 63) == 0) {
        int w = tid >> 6;
#pragma unroll
        for (int hh = 0; hh < 4; ++hh) { red[w][0][hh] = s4[hh]; red[w][1][hh] = d4[hh]; }
    }
    __syncthreads();
    if (tid < 4) ss[row * 4 + tid] = red[0][0][tid] + red[1][0][tid];
    else if (tid < 8) sd[row * 4 + tid - 4] = red[0][1][tid - 4] + red[1][1][tid - 4];
}

// ---------------- GEMM with acc export (for k_gat_h): [16,K]@[K,OTILE*128] ----------------
template <int K, int OTILE, int WKS, int WOS, int ORS, int OOS>
__device__ __forceinline__ void gemm16e(const float* __restrict__ Xs,
                                        const float* __restrict__ W,
                                        float* __restrict__ Out,
                                        float (&acc)[8][OTILE]) {
    const int tid = threadIdx.x;
    const int og = tid & 127;
    const int r0 = (tid >> 7) * 8;
#pragma unroll
    for (int r = 0; r < 8; ++r)
#pragma unroll
        for (int ot = 0; ot < OTILE; ++ot) acc[r][ot] = 0.f;
    for (int k = 0; k < K; k += 4) {
        float4 xv[8];
#pragma unroll
        for (int r = 0; r < 8; ++r)
            xv[r] = *(const float4*)(Xs + (r0 + r) * K + k);
#pragma unroll
        for (int ot = 0; ot < OTILE; ++ot) {
            const float* wp = W + ot * WOS + og;
            float w0 = wp[(k + 0) * WKS];
            float w1 = wp[(k + 1) * WKS];
            float w2 = wp[(k + 2) * WKS];
            float w3 = wp[(k + 3) * WKS];
#pragma unroll
            for (int r = 0; r < 8; ++r)
                acc[r][ot] += xv[r].x * w0 + xv[r].y * w1 + xv[r].z * w2 + xv[r].w * w3;
        }
    }
#pragma unroll
    for (int ot = 0; ot < OTILE; ++ot)
#pragma unroll
        for (int r = 0; r < 8; ++r)
            Out[(r0 + r) * ORS + ot * OOS + og] = acc[r][ot];
}

// ---------------- GAT layers 2-6: projection (F=128) + fused ss/sd ----------------
__global__ __launch_bounds__(256, 4) void k_gat_h(const float* __restrict__ x,
                                                  const float* __restrict__ W,
                                                  const float* __restrict__ asrc,
                                                  const float* __restrict__ adst,
                                                  float* __restrict__ h,
                                                  float* __restrict__ ss,
                                                  float* __restrict__ sd) {
    __shared__ __align__(16) float Xs[2048];
    __shared__ float sred[4][8][4], dred[4][8][4];
    int bid = blockIdx.x;
    int row0 = (((bid & 7) << 7) + (bid >> 3)) * 16;   // band swizzle, same XCD mapping
    int tid = threadIdx.x;
    for (int idx = tid; idx < 2048; idx += 256)
        Xs[idx] = x[(size_t)row0 * 128 + idx];
    __syncthreads();
    float acc[8][4];
    gemm16e<128, 4, 512, 128, 512, 128>(Xs, W, h + (size_t)row0 * 512, acc);
    int og = tid & 127, wave = tid >> 6;
#pragma unroll
    for (int r = 0; r < 8; ++r) {
#pragma unroll
        for (int ot = 0; ot < 4; ++ot) {
            float s = acc[r][ot] * asrc[ot * 128 + og];
            float d = acc[r][ot] * adst[ot * 128 + og];
#pragma unroll
            for (int off = 32; off; off >>= 1) {
                s += __shfl_xor(s, off, 64);
                d += __shfl_xor(d, off, 64);
            }
            if ((tid & 63) == 0) { sred[wave][r][ot] = s; dred[wave][r][ot] = d; }
        }
    }
    __syncthreads();
    if (tid < 64) {
        int r = tid >> 2, hh = tid & 3;
        int w0 = (r >> 3) * 2, rr = r & 7;
        ss[(row0 + r) * 4 + hh] = sred[w0][rr][hh] + sred[w0 + 1][rr][hh];
        sd[(row0 + r) * 4 + hh] = dred[w0][rr][hh] + dred[w0 + 1][rr][hh];
    }
}

// ---------------- GAT aggregation (segment softmax + gather), XCD-swizzled ----------------
__global__ __launch_bounds__(128) void k_agg(const float* __restrict__ h,
                                             const float* __restrict__ ss,
                                             const float* __restrict__ sd,
                                             const int* __restrict__ cnt,
                                             const int* __restrict__ nbr,
                                             const float* __restrict__ mfl,
                                             const float* __restrict__ bias,
                                             float* __restrict__ xo) {
    int bid = blockIdx.x;
    int row = ((bid & 7) << 11) + (bid >> 3);   // same-t rows colocate per XCD
    int tid = threadIdx.x;
    int t = row >> 10;
    if (mfl[row] == 0.f) { xo[(size_t)row * 128 + tid] = 0.f; return; }
    int c = cnt[row]; if (c > MAXDEG) c = MAXDEG;
    __shared__ int nb[MAXDEG];
    __shared__ float al[MAXDEG][4];
    if (tid < c) nb[tid] = nbr[(size_t)row * MAXDEG + tid];
    __syncthreads();
    for (int idx = tid; idx < c * 4; idx += 128) {
        int n = idx >> 2, hh = idx & 3, j = nb[n];
        float lg = sd[row * 4 + hh] + ss[(t * MM + j) * 4 + hh];
        al[n][hh] = lg > 0.f ? lg : 0.2f * lg;   // leaky_relu 0.2
    }
    __syncthreads();
    if (tid < 4) {
        float mx = -1e30f;
        for (int n = 0; n < c; ++n) mx = fmaxf(mx, al[n][tid]);
        float s = 0.f;
        for (int n = 0; n < c; ++n) { float e = __expf(al[n][tid] - mx); al[n][tid] = e; s += e; }
        float inv = 1.f / s;
        for (int n = 0; n < c; ++n) al[n][tid] *= inv;
    }
    __syncthreads();
    float a0 = 0, a1 = 0, a2 = 0, a3 = 0;
    for (int n = 0; n < c; ++n) {
        int j = nb[n];
        const float* hp = h + ((size_t)(t * MM + j)) * 512 + tid;
        a0 += al[n][0] * hp[0];
        a1 += al[n][1] * hp[128];
        a2 += al[n][2] * hp[256];
        a3 += al[n][3] * hp[384];
    }
    float v = 0.25f * (a0 + a1 + a2 + a3) + bias[tid];
    xo[(size_t)row * 128 + tid] = fmaxf(v, 0.f);
}

// ---------------- generic GEMM for k_tf: [16,K]@[K,OG*OTILE], scalar weight loads ----------
template <int K, int XSTR, int OG, int OTILE, int WK, int WOS, int OSTR, int OOS, int BOS>
__device__ __forceinline__ void gemmT(const float* __restrict__ Xs,
                                      const float* __restrict__ W,
                                      const float* __restrict__ bias,
                                      float* __restrict__ Out,
                                      bool accum, bool relu) {
    constexpr int RG = 256 / OG;
    constexpr int RT = 16 / RG;
    const int tid = threadIdx.x;
    const int og = tid % OG;
    const int r0 = (tid / OG) * RT;
    float acc[RT][OTILE];
#pragma unroll
    for (int r = 0; r < RT; ++r)
#pragma unroll
        for (int ot = 0; ot < OTILE; ++ot) acc[r][ot] = 0.f;
    for (int k = 0; k < K; k += 4) {
        float4 xv[RT];
#pragma unroll
        for (int r = 0; r < RT; ++r)
            xv[r] = *(const float4*)(Xs + (r0 + r) * XSTR + k);
#pragma unroll
        for (int ot = 0; ot < OTILE; ++ot) {
            const float* wp = W + ot * WOS + og;
            float w0 = wp[(k + 0) * WK];
            float w1 = wp[(k + 1) * WK];
            float w2 = wp[(k + 2) * WK];
            float w3 = wp[(k + 3) * WK];
#pragma unroll
            for (int r = 0; r < RT; ++r)
                acc[r][ot] += xv[r].x * w0 + xv[r].y * w1 + xv[r].z * w2 + xv[r].w * w3;
        }
    }
#pragma unroll
    for (int ot = 0; ot < OTILE; ++ot) {
        float bb = bias ? bias[ot * BOS + og] : 0.f;
#pragma unroll
        for (int r = 0; r < RT; ++r) {
            float v = acc[r][ot] + bb;
            if (relu) v = fmaxf(v, 0.f);
            float* op = Out + (r0 + r) * OSTR + ot * OOS + og;
            if (accum) *op += v; else *op = v;
        }
    }
}

// ---------------- in-place LayerNorm, 16 rows x 128, 256 threads ----------------
__device__ __forceinline__ void ln256(float* xs, const float* s, const float* b) {
    int tid = threadIdx.x, row = tid >> 4, lane = tid & 15;
    float* xr = xs + row * 128;
    float sum = 0.f;
#pragma unroll
    for (int k2 = 0; k2 < 8; ++k2) sum += xr[lane + 16 * k2];
#pragma unroll
    for (int off = 8; off; off >>= 1) sum += __shfl_xor(sum, off, 16);
    float mean = sum * (1.f / 128.f);
    float vs = 0.f;
#pragma unroll
    for (int k2 = 0; k2 < 8; ++k2) { float d = xr[lane + 16 * k2] - mean; vs += d * d; }
#pragma unroll
    for (int off = 8; off; off >>= 1) vs += __shfl_xor(vs, off, 16);
    float rstd = rsqrtf(vs * (1.f / 128.f) + 1e-5f);
#pragma unroll
    for (int k2 = 0; k2 < 8; ++k2) {
        int d = lane + 16 * k2;
        float v = (xr[d] - mean) * rstd;
        xr[d] = v * s[d] + b[d];
    }
    __syncthreads();
}

// ---------------- 5-layer transformer, 1 seq per 256-thread block ----------------
// LDS = 2048(xs) + 2*2112(q,k) + 2112(v/hid) + 1024(scores) = 9408 fl = 37632 B
// -> 4 blocks/CU, grid 1024 fully resident (no tail).
__global__ __launch_bounds__(256, 4) void k_tf(const float* __restrict__ xg,
        const float* __restrict__ Wqkv, const float* __restrict__ bqkv,
        const float* __restrict__ Wo,   const float* __restrict__ bo,
        const float* __restrict__ ln1s, const float* __restrict__ ln1b,
        const float* __restrict__ ln2s, const float* __restrict__ ln2b,
        const float* __restrict__ Wff1, const float* __restrict__ bff1,
        const float* __restrict__ Wff2, const float* __restrict__ bff2,
        float* __restrict__ out) {
    __shared__ __align__(16) float smem[9408];
    float* xs = smem;            // 2048: residual, stride 128
    float* qk = smem + 2048;     // q: stride 132; k at +2112; v at +4224 (OOS=2112)
    float* vb = smem + 6272;     // V in attention; FF1 hidden chunk in FF (stride 132)
    float* sb = smem + 8384;     // 1024: scores transposed [tk][hh*16+tq]
    int m = blockIdx.x, tid = threadIdx.x;

    // load + sinusoidal PE
    for (int idx = tid; idx < 2048; idx += 256) {
        int t = idx >> 7, d = idx & 127, jj = d >> 1;
        float arg = (float)t * expf(-(float)(2 * jj) * (9.210340371976184f / 128.f));
        float pe = (d & 1) ? cosf(arg) : sinf(arg);
        xs[idx] = xg[(size_t)t * (MM * HDIM) + (size_t)m * HDIM + d] + pe;
    }
    __syncthreads();

    for (int l = 0; l < 5; ++l) {
        // QKV fused: q->qk, k->qk+2112, v->qk+4224(=vb)
        gemmT<128, 128, 128, 3, 128, 16384, 132, 2112, 128>(
            xs, Wqkv + (size_t)l * 49152, bqkv + l * 384, qk, false, false);
        __syncthreads();
        // scores: thread = (hh, tq, tk0..tk0+3); write transposed sb[tk][hh*16+tq]
        {
            int hh = tid >> 6, tq = (tid >> 2) & 15, tk0 = (tid & 3) * 4;
            const float* qp = qk + tq * 132 + hh * 32;
            float a[4] = {0.f, 0.f, 0.f, 0.f};
#pragma unroll
            for (int d = 0; d < 8; ++d) {
                float4 q4 = *(const float4*)(qp + 4 * d);
#pragma unroll
                for (int j = 0; j < 4; ++j) {
                    float4 k4 = *(const float4*)(qk + 2112 + (tk0 + j) * 132 + hh * 32 + 4 * d);
                    a[j] += q4.x * k4.x + q4.y * k4.y + q4.z * k4.z + q4.w * k4.w;
                }
            }
#pragma unroll
            for (int j = 0; j < 4; ++j)
                sb[(tk0 + j) * 64 + hh * 16 + tq] = a[j] * 0.17677669529663687f;
        }
        __syncthreads();
        if (tid < 64) {   // softmax per (hh,tq) column, stride-64 (2-way, free)
            float mx = -1e30f;
#pragma unroll
            for (int u = 0; u < 16; ++u) mx = fmaxf(mx, sb[u * 64 + tid]);
            float s = 0.f;
#pragma unroll
            for (int u = 0; u < 16; ++u) { float e = __expf(sb[u * 64 + tid] - mx); sb[u * 64 + tid] = e; s += e; }
            float inv = 1.f / s;
#pragma unroll
            for (int u = 0; u < 16; ++u) sb[u * 64 + tid] *= inv;
        }
        __syncthreads();
        // O = P @ V -> q region (Q fully consumed before softmax barrier)
        {
            int o = tid & 127, r0p = (tid >> 7) * 8, hh = o >> 5;
            float accp[8] = {0, 0, 0, 0, 0, 0, 0, 0};
            for (int u = 0; u < 16; ++u) {
                float vv = vb[u * 132 + o];
                const float* pp = sb + u * 64 + hh * 16 + r0p;
#pragma unroll
                for (int r = 0; r < 8; ++r) accp[r] += pp[r] * vv;
            }
#pragma unroll
            for (int r = 0; r < 8; ++r) qk[(r0p + r) * 132 + o] = accp[r];
        }
        __syncthreads();
        // Wo: accumulate into residual xs (OG=64, OTILE=2 -> 4 b128 + 8 w per 32 FMA)
        gemmT<128, 132, 64, 2, 128, 64, 128, 64, 64>(
            qk, Wo + (size_t)l * 16384, bo + l * 128, xs, true, false);
        __syncthreads();
        ln256(xs, ln1s + l * 128, ln1b + l * 128);
        // FF: 4 chunks of 128 hidden; hid->vb, FF2 accumulates into q region
        for (int c = 0; c < 4; ++c) {
            gemmT<128, 128, 64, 2, 512, 64, 132, 64, 64>(
                xs, Wff1 + (size_t)l * 65536 + c * 128, bff1 + l * 512 + c * 128,
                vb, false, true);
            __syncthreads();
            gemmT<128, 132, 64, 2, 128, 64, 132, 64, 64>(
                vb, Wff2 + (size_t)l * 65536 + (size_t)c * 16384,
                c == 0 ? (bff2 + l * 128) : nullptr, qk, c != 0, false);
            __syncthreads();
        }
        for (int idx = tid; idx < 2048; idx += 256)
            xs[idx] += qk[(idx >> 7) * 132 + (idx & 127)];
        __syncthreads();
        ln256(xs, ln2s + l * 128, ln2b + l * 128);
    }
    for (int idx = tid; idx < 2048; idx += 256)
        out[(size_t)m * 2048 + idx] = xs[idx];
}

extern "C" void kernel_launch(void* const* d_in, const int* in_sizes, int n_in,
                              void* d_out, int out_size, void* d_ws, size_t ws_size,
                              hipStream_t stream) {
    (void)in_sizes; (void)n_in; (void)out_size; (void)ws_size;
    const int*   ego  = (const int*)d_in[0];
    const float* pos  = (const float*)d_in[1];
    const float* adj  = (const float*)d_in[2];
    const float* g1W  = (const float*)d_in[3];
    const float* g1as = (const float*)d_in[4];
    const float* g1ad = (const float*)d_in[5];
    const float* g1b  = (const float*)d_in[6];
    const float* gW   = (const float*)d_in[7];
    const float* gas  = (const float*)d_in[8];
    const float* gad  = (const float*)d_in[9];
    const float* gb   = (const float*)d_in[10];
    const float* Wqkv = (const float*)d_in[11];
    const float* bqkv = (const float*)d_in[12];
    const float* Wo   = (const float*)d_in[13];
    const float* bo   = (const float*)d_in[14];
    const float* l1s  = (const float*)d_in[15];
    const float* l1b  = (const float*)d_in[16];
    const float* l2s  = (const float*)d_in[17];
    const float* l2b  = (const float*)d_in[18];
    const float* Wff1 = (const float*)d_in[19];
    const float* bff1 = (const float*)d_in[20];
    const float* Wff2 = (const float*)d_in[21];
    const float* bff2 = (const float*)d_in[22];

    float* ws  = (float*)d_ws;
    float* x0  = ws;                       // 2,097,152 f
    float* x1  = x0 + 2097152;             // 2,097,152 f
    float* hb  = x1 + 2097152;             // 8,388,608 f
    float* ssb = hb + 8388608;             // 65,536 f
    float* sdb = ssb + 65536;              // 65,536 f
    float* mfl = sdb + 65536;              // 16,384 f
    int*   cnt = (int*)(mfl + 16384);      // 16,384 i
    int*   nbr = cnt + 16384;              // 1,048,576 i   (total ~55.2 MB)

    k_init<<<64, 256, 0, stream>>>(ego, mfl, cnt);
    k_edges<<<256, 256, 0, stream>>>(adj, mfl, cnt, nbr);

    // GAT layer 1 (F=2), projection + ss/sd fused
    k_gat1<<<NROWS, 128, 0, stream>>>(pos, g1W, g1as, g1ad, hb, ssb, sdb);
    k_agg<<<NROWS, 128, 0, stream>>>(hb, ssb, sdb, cnt, nbr, mfl, g1b, x0);

    float* xin = x0; float* xout = x1;
    for (int L = 0; L < 5; ++L) {
        k_gat_h<<<1024, 256, 0, stream>>>(xin, gW + (size_t)L * 65536,
                                          gas + L * 512, gad + L * 512, hb, ssb, sdb);
        k_agg<<<NROWS, 128, 0, stream>>>(hb, ssb, sdb, cnt, nbr, mfl, gb + L * 128, xout);
        float* tmp = xin; xin = xout; xout = tmp;
    }

    k_tf<<<MM, 256, 0, stream>>>(xin, Wqkv, bqkv, Wo, bo, l1s, l1b, l2s, l2b,
                                 Wff1, bff1, Wff2, bff2, (float*)d_out);
}